// Round 1
// baseline (648.406 us; speedup 1.0000x reference)
//
#include <hip/hip_runtime.h>
#include <cstddef>

// Problem constants (from setup_inputs): N=16, C=64, T=512, V=25, kernel=9, stride=2
#define N_  16
#define C_  64
#define T_  512
#define V_  25
#define E_  16            // C/4 (attention head dim)
#define S_  256           // T/stride (downsampled query rows)
#define KW_ 9             // band kernel width
#define M_  (T_ * V_)     // 12800 (rows of xp per n)
#define ROWSTRIDE (V_ * C_)  // 1600 floats between consecutive t rows of xp[n][t][v][d]

// -----------------------------------------------------------------------------
// Kernel A: xp[n][t*V+v][d] = sum_c x[n][c][t*V+v] * W[c][d]
// Batched GEMM, A is column-major in memory (x slice), B = W (64x64) in LDS.
// Thread layout: dg = tid&3 owns d-chunks {dg*4 + c*16}, mg = tid>>2 owns 4 m rows.
// Gives fully coalesced float4 loads of x and fully coalesced float4 stores of xp.
// -----------------------------------------------------------------------------
__global__ __launch_bounds__(256) void xp_gemm_kernel(
    const float* __restrict__ x, const float* __restrict__ W,
    float* __restrict__ xp)
{
    __shared__ float wl[C_ * C_];  // 16 KB
    int tid = threadIdx.x;
    #pragma unroll
    for (int i = 0; i < 4; ++i) {
        int idx = tid + i * 256;                 // 1024 float4 = 4096 floats
        ((float4*)wl)[idx] = ((const float4*)W)[idx];
    }
    __syncthreads();

    int dg = tid & 3;
    int mg = tid >> 2;
    int n  = blockIdx.y;
    int m0 = blockIdx.x * 256 + mg * 4;          // 4 consecutive m per thread
    const float* xb = x + (size_t)n * C_ * M_ + m0;

    float4 acc[4][4];                            // [m-sub j][d-chunk c]
    #pragma unroll
    for (int j = 0; j < 4; ++j)
        #pragma unroll
        for (int c = 0; c < 4; ++c) acc[j][c] = make_float4(0.f, 0.f, 0.f, 0.f);

    #pragma unroll 4
    for (int k = 0; k < C_; ++k) {
        float4 xv = *(const float4*)(xb + (size_t)k * M_);   // coalesced across mg
        #pragma unroll
        for (int c = 0; c < 4; ++c) {
            float4 wv = *(const float4*)(wl + k * C_ + c * 16 + dg * 4); // 4-way bcast
            acc[0][c].x += xv.x * wv.x; acc[0][c].y += xv.x * wv.y;
            acc[0][c].z += xv.x * wv.z; acc[0][c].w += xv.x * wv.w;
            acc[1][c].x += xv.y * wv.x; acc[1][c].y += xv.y * wv.y;
            acc[1][c].z += xv.y * wv.z; acc[1][c].w += xv.y * wv.w;
            acc[2][c].x += xv.z * wv.x; acc[2][c].y += xv.z * wv.y;
            acc[2][c].z += xv.z * wv.z; acc[2][c].w += xv.z * wv.w;
            acc[3][c].x += xv.w * wv.x; acc[3][c].y += xv.w * wv.y;
            acc[3][c].z += xv.w * wv.z; acc[3][c].w += xv.w * wv.w;
        }
    }
    // store: instr (j,c): lanes dg=0..3 write consecutive 16B -> full 64B lines
    float* ob = xp + ((size_t)n * M_ + m0) * C_;
    #pragma unroll
    for (int j = 0; j < 4; ++j)
        #pragma unroll
        for (int c = 0; c < 4; ++c)
            *(float4*)(ob + (size_t)j * C_ + c * 16 + dg * 4) = acc[j][c];
}

// -----------------------------------------------------------------------------
// Kernel B: one block per (n,v). 256 threads; thread s owns downsampled query
// row s (t_q = 2s).
//   phase 1: kk[512][16] into LDS, q[16] into regs (alpha/phi staged in LDS).
//   pass 1 : softmax denominator (max-free: |att| <~ 3, exp is safe in fp32).
//   pass 2 : recompute att, p = exp(a/16)/l + band, acc[d] += p * xp[t][d]
//            with xp staged in 64-row LDS tiles (all-lane broadcast reads).
//   output : out[n][d][s][v] (already transposed).
// -----------------------------------------------------------------------------
__global__ __launch_bounds__(256) void attn_kernel(
    const float* __restrict__ xp, const float* __restrict__ alpha,
    const float* __restrict__ phi, const float* __restrict__ kband,
    float* __restrict__ out)
{
    __shared__ float kkl[T_ * E_];     // 32 KB: kk keys
    __shared__ float xpt[64 * C_];     // 16 KB: xp tile (also alpha/phi staging)
    __shared__ float kbl[16];          // band taps

    int tid = threadIdx.x;
    int nv = blockIdx.x;
    int n = nv / V_, v = nv - n * V_;
    const float* xpb = xp + (size_t)n * M_ * C_ + (size_t)v * C_; // + t*ROWSTRIDE

    if (tid < KW_) kbl[tid] = kband[tid];
    // stage alpha (xpt[0..1023]) and phi (xpt[1024..2047])
    for (int i = tid; i < 2048; i += 256)
        xpt[i] = (i < 1024) ? alpha[i] : phi[i - 1024];
    __syncthreads();

    const float* als = xpt;
    const float* phs = xpt + 1024;

    // ---- kk rows: thread handles t = tid and t = tid+256 ----
    #pragma unroll
    for (int r = 0; r < 2; ++r) {
        int t = tid + r * 256;
        const float4* xr = (const float4*)(xpb + (size_t)t * ROWSTRIDE);
        float a[E_];
        #pragma unroll
        for (int e = 0; e < E_; ++e) a[e] = 0.f;
        #pragma unroll
        for (int d4 = 0; d4 < 16; ++d4) {
            float4 xv = xr[d4];
            #pragma unroll
            for (int e4 = 0; e4 < 4; ++e4) {
                float4 p0 = *(const float4*)(phs + (d4*4+0)*E_ + e4*4);
                float4 p1 = *(const float4*)(phs + (d4*4+1)*E_ + e4*4);
                float4 p2 = *(const float4*)(phs + (d4*4+2)*E_ + e4*4);
                float4 p3 = *(const float4*)(phs + (d4*4+3)*E_ + e4*4);
                a[e4*4+0] += xv.x*p0.x + xv.y*p1.x + xv.z*p2.x + xv.w*p3.x;
                a[e4*4+1] += xv.x*p0.y + xv.y*p1.y + xv.z*p2.y + xv.w*p3.y;
                a[e4*4+2] += xv.x*p0.z + xv.y*p1.z + xv.z*p2.z + xv.w*p3.z;
                a[e4*4+3] += xv.x*p0.w + xv.y*p1.w + xv.z*p2.w + xv.w*p3.w;
            }
        }
        #pragma unroll
        for (int e4 = 0; e4 < 4; ++e4)
            *(float4*)(kkl + t * E_ + e4 * 4) =
                make_float4(a[e4*4], a[e4*4+1], a[e4*4+2], a[e4*4+3]);
    }

    // ---- q row for this thread's query (t = 2*tid) ----
    float q[E_];
    {
        const float4* xr = (const float4*)(xpb + (size_t)(2 * tid) * ROWSTRIDE);
        #pragma unroll
        for (int e = 0; e < E_; ++e) q[e] = 0.f;
        #pragma unroll
        for (int d4 = 0; d4 < 16; ++d4) {
            float4 xv = xr[d4];
            #pragma unroll
            for (int e4 = 0; e4 < 4; ++e4) {
                float4 p0 = *(const float4*)(als + (d4*4+0)*E_ + e4*4);
                float4 p1 = *(const float4*)(als + (d4*4+1)*E_ + e4*4);
                float4 p2 = *(const float4*)(als + (d4*4+2)*E_ + e4*4);
                float4 p3 = *(const float4*)(als + (d4*4+3)*E_ + e4*4);
                q[e4*4+0] += xv.x*p0.x + xv.y*p1.x + xv.z*p2.x + xv.w*p3.x;
                q[e4*4+1] += xv.x*p0.y + xv.y*p1.y + xv.z*p2.y + xv.w*p3.y;
                q[e4*4+2] += xv.x*p0.z + xv.y*p1.z + xv.z*p2.z + xv.w*p3.z;
                q[e4*4+3] += xv.x*p0.w + xv.y*p1.w + xv.z*p2.w + xv.w*p3.w;
            }
        }
    }
    __syncthreads();

    // ---- pass 1: softmax denominator ----
    float l = 0.f;
    for (int t = 0; t < T_; ++t) {
        const float4* kr = (const float4*)(kkl + t * E_);
        float4 k0 = kr[0], k1 = kr[1], k2 = kr[2], k3 = kr[3];
        float a = q[0]*k0.x + q[1]*k0.y + q[2]*k0.z + q[3]*k0.w
                + q[4]*k1.x + q[5]*k1.y + q[6]*k1.z + q[7]*k1.w
                + q[8]*k2.x + q[9]*k2.y + q[10]*k2.z + q[11]*k2.w
                + q[12]*k3.x + q[13]*k3.y + q[14]*k3.z + q[15]*k3.w;
        l += __expf(a * 0.0625f);
    }
    float rl = 1.f / l;

    // ---- pass 2: recompute att, accumulate PV ----
    float acc[C_];
    #pragma unroll
    for (int d = 0; d < C_; ++d) acc[d] = 0.f;
    int s2 = 2 * tid;  // this thread's query row in t-space

    for (int tile = 0; tile < 8; ++tile) {
        __syncthreads();   // protect xpt reuse (incl. alpha/phi area on tile 0)
        int t0 = tile * 64;
        {   // cooperative load of 64 xp rows: wave-contiguous LDS writes
            int rr = tid >> 4, cc = tid & 15;
            #pragma unroll
            for (int i = 0; i < 4; ++i) {
                int row = rr + i * 16;
                float4 xv = *(const float4*)(xpb + (size_t)(t0 + row) * ROWSTRIDE + cc * 4);
                *(float4*)(xpt + row * C_ + cc * 4) = xv;
            }
        }
        __syncthreads();
        for (int tt = 0; tt < 64; ++tt) {
            int t = t0 + tt;
            const float4* kr = (const float4*)(kkl + t * E_);
            float4 k0 = kr[0], k1 = kr[1], k2 = kr[2], k3 = kr[3];
            float a = q[0]*k0.x + q[1]*k0.y + q[2]*k0.z + q[3]*k0.w
                    + q[4]*k1.x + q[5]*k1.y + q[6]*k1.z + q[7]*k1.w
                    + q[8]*k2.x + q[9]*k2.y + q[10]*k2.z + q[11]*k2.w
                    + q[12]*k3.x + q[13]*k3.y + q[14]*k3.z + q[15]*k3.w;
            float p = __expf(a * 0.0625f) * rl;
            unsigned bi = (unsigned)(t - s2 + 4);
            if (bi < 9u) p += kbl[bi];          // banded I[2s, t] (post-softmax add)
            const float4* xr = (const float4*)(xpt + tt * C_);
            #pragma unroll
            for (int d4 = 0; d4 < 16; ++d4) {
                float4 xv = xr[d4];
                acc[d4*4+0] += p * xv.x;
                acc[d4*4+1] += p * xv.y;
                acc[d4*4+2] += p * xv.z;
                acc[d4*4+3] += p * xv.w;
            }
        }
    }

    // ---- write out[n][d][s][v], s = tid ----
    float* ob = out + (size_t)n * C_ * S_ * V_ + (size_t)tid * V_ + v;
    #pragma unroll
    for (int d = 0; d < C_; ++d)
        ob[(size_t)d * (S_ * V_)] = acc[d];
}

// -----------------------------------------------------------------------------
extern "C" void kernel_launch(void* const* d_in, const int* in_sizes, int n_in,
                              void* d_out, int out_size, void* d_ws, size_t ws_size,
                              hipStream_t stream)
{
    const float* x     = (const float*)d_in[0];
    const float* W     = (const float*)d_in[1];
    const float* alpha = (const float*)d_in[2];
    const float* phi   = (const float*)d_in[3];
    const float* kband = (const float*)d_in[4];
    // d_in[5] = kernel(9), d_in[6] = stride(2): compile-time constants here.

    float* xp = (float*)d_ws;  // needs N_*M_*C_*4 = 52,428,800 bytes of scratch

    xp_gemm_kernel<<<dim3(M_ / 256, N_), 256, 0, stream>>>(x, W, xp);
    attn_kernel<<<dim3(N_ * V_), 256, 0, stream>>>(xp, alpha, phi, kband,
                                                   (float*)d_out);
}

// Round 2
// 338.605 us; speedup vs baseline: 1.9149x; 1.9149x over previous
//
#include <hip/hip_runtime.h>
#include <cstddef>

// Problem constants: N=16, C=64, T=512, V=25, kernel=9, stride=2
#define N_  16
#define C_  64
#define T_  512
#define V_  25
#define E_  16            // C/4
#define S_  256           // T/stride
#define M_  (T_ * V_)     // 12800
#define RS_ (V_ * C_)     // 1600 floats between consecutive t rows of xp[n][t][v][d]
#define TT_ 32            // t-tile
#define NTILE_ (T_ / TT_) // 16

// ---- attn LDS layout (floats). Total 16256 floats = 65,024 B (<= 64 KiB) ----
#define PT_OFF    0        // p_t[32][260]   (stride 260: bank-spread, 16B aligned)
#define PT_STRIDE 260
#define XT_OFF    8320     // xp_tile[32][68]
#define XT_STRIDE 68
#define QT_OFF    10496    // q_t[16][256]
#define KK_OFF    14592    // kk_t[16][36]
#define KK_STRIDE 36
#define PHI_OFF   15168    // phi_t[16][68]
#define AL_OFF    PT_OFF   // alpha[64][16] raw, aliases p_t (phase 0 only)
#define LS_OFF    KK_OFF   // l_s[256], aliases kk_t (epilogue only)
#define KB_OFF    (KK_OFF + 256) // kb[9], aliases kk_t tail (epilogue only)
#define SMEM_FLOATS 16256

__device__ __forceinline__ float4 f4fma(float s, float4 a, float4 d) {
    d.x += s * a.x; d.y += s * a.y; d.z += s * a.z; d.w += s * a.w; return d;
}
__device__ __forceinline__ float4 f4scale(float4 a, float s) {
    a.x *= s; a.y *= s; a.z *= s; a.w *= s; return a;
}

// -----------------------------------------------------------------------------
// Kernel A: xp[n][m][d] = sum_c x[n][c][m] * W[c][d], m = t*V+v.
// x-tile staged through LDS with fully-coalesced 1KB/instr loads.
// -----------------------------------------------------------------------------
__global__ __launch_bounds__(256) void xp_gemm_kernel(
    const float* __restrict__ x, const float* __restrict__ W,
    float* __restrict__ xp)
{
    __shared__ float wl[C_ * C_];   // 16 KB
    __shared__ float xt[32 * 256];  // 32 KB
    const int tid = threadIdx.x;
    #pragma unroll
    for (int i = 0; i < 4; ++i)
        ((float4*)wl)[tid + i * 256] = ((const float4*)W)[tid + i * 256];

    const int n  = blockIdx.y;
    const int m0 = blockIdx.x * 256;
    const float* xb = x + (size_t)n * C_ * M_ + m0;

    float4 acc[16];
    #pragma unroll
    for (int d4 = 0; d4 < 16; ++d4) acc[d4] = make_float4(0.f, 0.f, 0.f, 0.f);

    for (int h = 0; h < 2; ++h) {
        __syncthreads();
        #pragma unroll
        for (int i = 0; i < 8; ++i) {          // stage 32 k-rows x 256 m
            int id = tid + i * 256;
            int row = id >> 6, col = id & 63;  // lanes cover 1KB contiguous
            *(float4*)(xt + row * 256 + col * 4) =
                *(const float4*)(xb + (size_t)(h * 32 + row) * M_ + col * 4);
        }
        __syncthreads();
        #pragma unroll 8
        for (int k = 0; k < 32; ++k) {
            float xv = xt[k * 256 + tid];
            const float4* wr = (const float4*)(wl + (h * 32 + k) * C_);
            #pragma unroll
            for (int d4 = 0; d4 < 16; ++d4) acc[d4] = f4fma(xv, wr[d4], acc[d4]);
        }
    }
    float* ob = xp + ((size_t)n * M_ + m0 + tid) * C_;
    #pragma unroll
    for (int d4 = 0; d4 < 16; ++d4) *(float4*)(ob + d4 * 4) = acc[d4];
}

// -----------------------------------------------------------------------------
// Kernel B: one block per (n,v), 256 threads.
//  - q_t[16][256] from global xp rows (t=2s) x alpha (broadcast LDS reads)
//  - per 32-t tile: stage xp_tile -> kk_t (from LDS) -> p_t = exp(q.k/16)
//    (unnormalized, max-free) -> l accumulation + PV GEMM with 8s x 8d
//    register tiles (4 FMA per LDS float, broadcast-heavy reads).
//  - epilogue: scale by 1/l, add band taps from global xp (L2-hot), store.
// -----------------------------------------------------------------------------
__global__ __launch_bounds__(256) void attn_kernel(
    const float* __restrict__ xp, const float* __restrict__ alpha,
    const float* __restrict__ phi, const float* __restrict__ kband,
    float* __restrict__ outbuf, int direct_out)
{
    __shared__ float sm[SMEM_FLOATS];
    const int tid = threadIdx.x;
    const int nv = blockIdx.x;
    const int n = nv / V_, v = nv - n * V_;
    const float* xpb = xp + (size_t)n * M_ * C_ + (size_t)v * C_;

    // ---- phase 0: stage alpha (raw, into p_t region) + phi (transposed) ----
    for (int i = tid; i < 1024; i += 256) {
        sm[AL_OFF + i] = alpha[i];
        int e = i & 15, d = i >> 4;
        sm[PHI_OFF + e * XT_STRIDE + d] = phi[i];
    }
    __syncthreads();

    // ---- q_t[e][s]: thread s=tid, query row t=2s ----
    {
        const float4* xr = (const float4*)(xpb + (size_t)(2 * tid) * RS_);
        float4 q0 = make_float4(0.f,0.f,0.f,0.f), q1 = q0, q2 = q0, q3 = q0;
        #pragma unroll
        for (int d4 = 0; d4 < 16; ++d4) {
            float4 xv = xr[d4];
            const float4* a0 = (const float4*)(sm + AL_OFF + (d4 * 4 + 0) * 16);
            const float4* a1 = (const float4*)(sm + AL_OFF + (d4 * 4 + 1) * 16);
            const float4* a2 = (const float4*)(sm + AL_OFF + (d4 * 4 + 2) * 16);
            const float4* a3 = (const float4*)(sm + AL_OFF + (d4 * 4 + 3) * 16);
            q0 = f4fma(xv.x, a0[0], q0); q1 = f4fma(xv.x, a0[1], q1);
            q2 = f4fma(xv.x, a0[2], q2); q3 = f4fma(xv.x, a0[3], q3);
            q0 = f4fma(xv.y, a1[0], q0); q1 = f4fma(xv.y, a1[1], q1);
            q2 = f4fma(xv.y, a1[2], q2); q3 = f4fma(xv.y, a1[3], q3);
            q0 = f4fma(xv.z, a2[0], q0); q1 = f4fma(xv.z, a2[1], q1);
            q2 = f4fma(xv.z, a2[2], q2); q3 = f4fma(xv.z, a2[3], q3);
            q0 = f4fma(xv.w, a3[0], q0); q1 = f4fma(xv.w, a3[1], q1);
            q2 = f4fma(xv.w, a3[2], q2); q3 = f4fma(xv.w, a3[3], q3);
        }
        sm[QT_OFF +  0 * 256 + tid] = q0.x; sm[QT_OFF +  1 * 256 + tid] = q0.y;
        sm[QT_OFF +  2 * 256 + tid] = q0.z; sm[QT_OFF +  3 * 256 + tid] = q0.w;
        sm[QT_OFF +  4 * 256 + tid] = q1.x; sm[QT_OFF +  5 * 256 + tid] = q1.y;
        sm[QT_OFF +  6 * 256 + tid] = q1.z; sm[QT_OFF +  7 * 256 + tid] = q1.w;
        sm[QT_OFF +  8 * 256 + tid] = q2.x; sm[QT_OFF +  9 * 256 + tid] = q2.y;
        sm[QT_OFF + 10 * 256 + tid] = q2.z; sm[QT_OFF + 11 * 256 + tid] = q2.w;
        sm[QT_OFF + 12 * 256 + tid] = q3.x; sm[QT_OFF + 13 * 256 + tid] = q3.y;
        sm[QT_OFF + 14 * 256 + tid] = q3.z; sm[QT_OFF + 15 * 256 + tid] = q3.w;
    }

    const int sg = tid >> 3, dg = tid & 7;     // PV: 8s x 8d per thread
    const int s0 = sg * 8, d0 = dg * 8;
    const int qsg = sg, qtg = dg;              // QK: 4t x 8s per thread

    float4 accA[8], accB[8];
    #pragma unroll
    for (int i = 0; i < 8; ++i) { accA[i] = make_float4(0.f,0.f,0.f,0.f); accB[i] = accA[i]; }
    float lacc = 0.f;

    for (int it = 0; it < NTILE_; ++it) {
        const int t0 = it * TT_;
        __syncthreads();
        // stage xp_tile[32][68]
        #pragma unroll
        for (int rep = 0; rep < 2; ++rep) {
            int id = tid + rep * 256;
            int row = id >> 4, c4 = (id & 15) * 4;
            *(float4*)(sm + XT_OFF + row * XT_STRIDE + c4) =
                *(const float4*)(xpb + (size_t)(t0 + row) * RS_ + c4);
        }
        __syncthreads();
        // kk_t: thread t=tid>>3, e in {ep, ep+8}
        {
            int t = tid >> 3, ep = tid & 7;
            const float4* xr4 = (const float4*)(sm + XT_OFF + t * XT_STRIDE);
            const float4* p0  = (const float4*)(sm + PHI_OFF + ep * XT_STRIDE);
            const float4* p1  = (const float4*)(sm + PHI_OFF + (ep + 8) * XT_STRIDE);
            float4 a0 = make_float4(0.f,0.f,0.f,0.f), a1 = a0;
            #pragma unroll
            for (int d4 = 0; d4 < 16; ++d4) {
                float4 xv = xr4[d4];
                float4 b0 = p0[d4], b1 = p1[d4];
                a0.x += xv.x*b0.x; a0.y += xv.y*b0.y; a0.z += xv.z*b0.z; a0.w += xv.w*b0.w;
                a1.x += xv.x*b1.x; a1.y += xv.y*b1.y; a1.z += xv.z*b1.z; a1.w += xv.w*b1.w;
            }
            sm[KK_OFF + ep * KK_STRIDE + t]       = a0.x + a0.y + a0.z + a0.w;
            sm[KK_OFF + (ep + 8) * KK_STRIDE + t] = a1.x + a1.y + a1.z + a1.w;
        }
        __syncthreads();
        // QK -> p_t (unnormalized exp)
        {
            float4 a00 = make_float4(0.f,0.f,0.f,0.f), a01 = a00, a10 = a00, a11 = a00,
                   a20 = a00, a21 = a00, a30 = a00, a31 = a00;
            const float* kkp = sm + KK_OFF + qtg * 4;
            const float* qp  = sm + QT_OFF + qsg * 8;
            #pragma unroll
            for (int e = 0; e < 16; ++e) {
                float4 kv = *(const float4*)(kkp + e * KK_STRIDE);
                float4 u0 = *(const float4*)(qp + e * 256);
                float4 u1 = *(const float4*)(qp + e * 256 + 4);
                a00 = f4fma(kv.x, u0, a00); a01 = f4fma(kv.x, u1, a01);
                a10 = f4fma(kv.y, u0, a10); a11 = f4fma(kv.y, u1, a11);
                a20 = f4fma(kv.z, u0, a20); a21 = f4fma(kv.z, u1, a21);
                a30 = f4fma(kv.w, u0, a30); a31 = f4fma(kv.w, u1, a31);
            }
            float* pb = sm + PT_OFF + (qtg * 4) * PT_STRIDE + qsg * 8;
            float4 r0, r1;
            r0.x = __expf(a00.x*0.0625f); r0.y = __expf(a00.y*0.0625f);
            r0.z = __expf(a00.z*0.0625f); r0.w = __expf(a00.w*0.0625f);
            r1.x = __expf(a01.x*0.0625f); r1.y = __expf(a01.y*0.0625f);
            r1.z = __expf(a01.z*0.0625f); r1.w = __expf(a01.w*0.0625f);
            *(float4*)(pb) = r0; *(float4*)(pb + 4) = r1;
            r0.x = __expf(a10.x*0.0625f); r0.y = __expf(a10.y*0.0625f);
            r0.z = __expf(a10.z*0.0625f); r0.w = __expf(a10.w*0.0625f);
            r1.x = __expf(a11.x*0.0625f); r1.y = __expf(a11.y*0.0625f);
            r1.z = __expf(a11.z*0.0625f); r1.w = __expf(a11.w*0.0625f);
            *(float4*)(pb + PT_STRIDE) = r0; *(float4*)(pb + PT_STRIDE + 4) = r1;
            r0.x = __expf(a20.x*0.0625f); r0.y = __expf(a20.y*0.0625f);
            r0.z = __expf(a20.z*0.0625f); r0.w = __expf(a20.w*0.0625f);
            r1.x = __expf(a21.x*0.0625f); r1.y = __expf(a21.y*0.0625f);
            r1.z = __expf(a21.z*0.0625f); r1.w = __expf(a21.w*0.0625f);
            *(float4*)(pb + 2 * PT_STRIDE) = r0; *(float4*)(pb + 2 * PT_STRIDE + 4) = r1;
            r0.x = __expf(a30.x*0.0625f); r0.y = __expf(a30.y*0.0625f);
            r0.z = __expf(a30.z*0.0625f); r0.w = __expf(a30.w*0.0625f);
            r1.x = __expf(a31.x*0.0625f); r1.y = __expf(a31.y*0.0625f);
            r1.z = __expf(a31.z*0.0625f); r1.w = __expf(a31.w*0.0625f);
            *(float4*)(pb + 3 * PT_STRIDE) = r0; *(float4*)(pb + 3 * PT_STRIDE + 4) = r1;
        }
        __syncthreads();
        // l accumulation (column tid)
        {
            const float* pc = sm + PT_OFF + tid;
            float s = 0.f;
            #pragma unroll 8
            for (int tt = 0; tt < TT_; ++tt) s += pc[tt * PT_STRIDE];
            lacc += s;
        }
        // PV GEMM: acc[8s][8d] += p_t[tt][s0:8] * xp_tile[tt][d0:8]
        {
            const float* pp = sm + PT_OFF + s0;
            const float* xx = sm + XT_OFF + d0;
            #pragma unroll 4
            for (int tt = 0; tt < TT_; ++tt) {
                float4 p0 = *(const float4*)(pp + tt * PT_STRIDE);
                float4 p1 = *(const float4*)(pp + tt * PT_STRIDE + 4);
                float4 x0 = *(const float4*)(xx + tt * XT_STRIDE);
                float4 x1 = *(const float4*)(xx + tt * XT_STRIDE + 4);
                accA[0] = f4fma(p0.x, x0, accA[0]); accB[0] = f4fma(p0.x, x1, accB[0]);
                accA[1] = f4fma(p0.y, x0, accA[1]); accB[1] = f4fma(p0.y, x1, accB[1]);
                accA[2] = f4fma(p0.z, x0, accA[2]); accB[2] = f4fma(p0.z, x1, accB[2]);
                accA[3] = f4fma(p0.w, x0, accA[3]); accB[3] = f4fma(p0.w, x1, accB[3]);
                accA[4] = f4fma(p1.x, x0, accA[4]); accB[4] = f4fma(p1.x, x1, accB[4]);
                accA[5] = f4fma(p1.y, x0, accA[5]); accB[5] = f4fma(p1.y, x1, accB[5]);
                accA[6] = f4fma(p1.z, x0, accA[6]); accB[6] = f4fma(p1.z, x1, accB[6]);
                accA[7] = f4fma(p1.w, x0, accA[7]); accB[7] = f4fma(p1.w, x1, accB[7]);
            }
        }
    }

    // ---- epilogue: publish l (aliases kk_t region, safe: p_t/xp only read now)
    sm[LS_OFF + tid] = lacc;
    if (tid < 9) sm[KB_OFF + tid] = kband[tid];
    __syncthreads();

    #pragma unroll
    for (int si = 0; si < 8; ++si) {
        float rl = 1.0f / sm[LS_OFF + s0 + si];
        accA[si] = f4scale(accA[si], rl);
        accB[si] = f4scale(accB[si], rl);
    }
    // band: out += kb[j] * xp[2s+j-4][d0:8]
    #pragma unroll
    for (int si = 0; si < 8; ++si) {
        int s = s0 + si;
        #pragma unroll
        for (int j = 0; j < 9; ++j) {
            int t = 2 * s + j - 4;
            if ((unsigned)t < (unsigned)T_) {
                float kb = sm[KB_OFF + j];
                const float* xr = xpb + (size_t)t * RS_ + d0;
                accA[si] = f4fma(kb, *(const float4*)xr, accA[si]);
                accB[si] = f4fma(kb, *(const float4*)(xr + 4), accB[si]);
            }
        }
    }
    // store
    if (!direct_out) {
        float* ob = outbuf + ((size_t)(n * V_ + v) * S_) * C_;
        #pragma unroll
        for (int si = 0; si < 8; ++si) {
            *(float4*)(ob + (size_t)(s0 + si) * C_ + d0)     = accA[si];
            *(float4*)(ob + (size_t)(s0 + si) * C_ + d0 + 4) = accB[si];
        }
    } else {
        float* ob = outbuf + (size_t)n * (C_ * S_ * V_) + v;
        #pragma unroll
        for (int si = 0; si < 8; ++si) {
            float* b = ob + (size_t)(s0 + si) * V_;
            b[(size_t)(d0+0)*(S_*V_)] = accA[si].x; b[(size_t)(d0+1)*(S_*V_)] = accA[si].y;
            b[(size_t)(d0+2)*(S_*V_)] = accA[si].z; b[(size_t)(d0+3)*(S_*V_)] = accA[si].w;
            b[(size_t)(d0+4)*(S_*V_)] = accB[si].x; b[(size_t)(d0+5)*(S_*V_)] = accB[si].y;
            b[(size_t)(d0+6)*(S_*V_)] = accB[si].z; b[(size_t)(d0+7)*(S_*V_)] = accB[si].w;
        }
    }
}

// -----------------------------------------------------------------------------
// Kernel C: transpose tmp[n][v][s][d] -> out[n][d][s][v] via LDS tile.
// Block = (n, s-tile of 8). Reads & writes coalesced.
// -----------------------------------------------------------------------------
__global__ __launch_bounds__(256) void transpose_kernel(
    const float* __restrict__ tmp, float* __restrict__ out)
{
    __shared__ float lt[V_ * 8 * 65];   // 52 KB
    const int tid = threadIdx.x;
    const int b = blockIdx.x;
    const int n = b >> 5, st = b & 31, s0 = st * 8;
    const float* tb = tmp + ((size_t)n * V_ * S_ + s0) * C_;
    for (int i = tid; i < V_ * 8 * 16; i += 256) {      // 3200 float4
        int vv = i >> 7, r = i & 127;
        int si = r >> 4, c4 = (r & 15) * 4;
        float4 xv = *(const float4*)(tb + (size_t)vv * S_ * C_ + si * C_ + c4);
        float* dst = lt + (vv * 8 + si) * 65 + c4;
        dst[0] = xv.x; dst[1] = xv.y; dst[2] = xv.z; dst[3] = xv.w;
    }
    __syncthreads();
    float* ob = out + (size_t)n * (C_ * S_ * V_) + (size_t)s0 * V_;
    for (int i = tid; i < C_ * 8 * V_; i += 256) {      // 12800 floats
        int d = i / 200;
        int r = i - d * 200;
        int si = r / 25;
        int vv = r - si * 25;
        ob[(size_t)d * (S_ * V_) + si * V_ + vv] = lt[(vv * 8 + si) * 65 + d];
    }
}

// -----------------------------------------------------------------------------
extern "C" void kernel_launch(void* const* d_in, const int* in_sizes, int n_in,
                              void* d_out, int out_size, void* d_ws, size_t ws_size,
                              hipStream_t stream)
{
    const float* x     = (const float*)d_in[0];
    const float* W     = (const float*)d_in[1];
    const float* alpha = (const float*)d_in[2];
    const float* phi   = (const float*)d_in[3];
    const float* kband = (const float*)d_in[4];

    const size_t XP_BYTES  = (size_t)N_ * M_ * C_ * 4;   // 52,428,800
    const size_t TMP_BYTES = (size_t)N_ * V_ * S_ * C_ * 4; // 26,214,400
    float* xp  = (float*)d_ws;
    const bool use_tmp = ws_size >= XP_BYTES + TMP_BYTES;
    float* tmp = (float*)((char*)d_ws + XP_BYTES);

    xp_gemm_kernel<<<dim3(M_ / 256, N_), 256, 0, stream>>>(x, W, xp);
    attn_kernel<<<dim3(N_ * V_), 256, 0, stream>>>(
        xp, alpha, phi, kband,
        use_tmp ? tmp : (float*)d_out, use_tmp ? 0 : 1);
    if (use_tmp)
        transpose_kernel<<<dim3(N_ * 32), 256, 0, stream>>>(tmp, (float*)d_out);
}

// Round 3
// 285.637 us; speedup vs baseline: 2.2700x; 1.1854x over previous
//
#include <hip/hip_runtime.h>
#include <cstddef>

// Problem constants: N=16, C=64, T=512, V=25, kernel=9, stride=2
#define N_  16
#define C_  64
#define T_  512
#define V_  25
#define S_  256
#define M_  (T_ * V_)      // 12800
#define RS_ (V_ * C_)      // 1600 floats between consecutive t rows of xp[n][t][v][d]

typedef short s16x4 __attribute__((ext_vector_type(4)));
typedef float f32x4 __attribute__((ext_vector_type(4)));

// ---- MFMA 16x16x16 bf16 (D = A*B + C), hedged across builtin spellings ----
__device__ __forceinline__ f32x4 mfma16(s16x4 a, s16x4 b, f32x4 c) {
#if __has_builtin(__builtin_amdgcn_mfma_f32_16x16x16_bf16)
    return __builtin_amdgcn_mfma_f32_16x16x16_bf16(a, b, c, 0, 0, 0);
#elif __has_builtin(__builtin_amdgcn_mfma_f32_16x16x16bf16_1k)
    return __builtin_amdgcn_mfma_f32_16x16x16bf16_1k(a, b, c, 0, 0, 0);
#else
    asm volatile("v_mfma_f32_16x16x16_bf16 %0, %1, %2, %0" : "+v"(c) : "v"(a), "v"(b));
    return c;
#endif
}

// fp32 -> (bf16 hi, bf16 lo) split; packed as u32 = hi | (lo << 16)
__device__ __forceinline__ unsigned packhl(float f) {
    unsigned fb = __float_as_uint(f);
    float hf = __uint_as_float(fb & 0xffff0000u);
    unsigned lb = __float_as_uint(f - hf);
    return (fb >> 16) | (lb & 0xffff0000u);
}
__device__ __forceinline__ unsigned short bhi(float f) {
    return (unsigned short)(__float_as_uint(f) >> 16);
}
__device__ __forceinline__ unsigned short blo(float f) {
    unsigned fb = __float_as_uint(f);
    float hf = __uint_as_float(fb & 0xffff0000u);
    return (unsigned short)(__float_as_uint(f - hf) >> 16);
}
__device__ __forceinline__ s16x4 hi4(uint4 q) {
    return s16x4{(short)(q.x & 0xffffu), (short)(q.y & 0xffffu),
                 (short)(q.z & 0xffffu), (short)(q.w & 0xffffu)};
}
__device__ __forceinline__ s16x4 lo4(uint4 q) {
    return s16x4{(short)(q.x >> 16), (short)(q.y >> 16),
                 (short)(q.z >> 16), (short)(q.w >> 16)};
}
__device__ __forceinline__ s16x4 mk_hi(float a, float b, float c, float d) {
    return s16x4{(short)bhi(a), (short)bhi(b), (short)bhi(c), (short)bhi(d)};
}
__device__ __forceinline__ s16x4 mk_lo(float a, float b, float c, float d) {
    return s16x4{(short)blo(a), (short)blo(b), (short)blo(c), (short)blo(d)};
}

// -----------------------------------------------------------------------------
// Kernel A: xp[n][m][d] = sum_c x[n][c][m] * W[c][d] via bf16x3 MFMA.
// No LDS: A-frags read straight from global (quarter-wave 64B segments, L1/L2
// friendly); W (16 KB) is L1-resident.  Wave owns 64 m x 64 d.
// -----------------------------------------------------------------------------
__global__ __launch_bounds__(256, 4) void xp_gemm_kernel(
    const float* __restrict__ x, const float* __restrict__ W,
    float* __restrict__ xp)
{
    const int tid = threadIdx.x, lane = tid & 63, wid = tid >> 6;
    const int l15 = lane & 15, oct = lane >> 4;
    const int n = blockIdx.y;
    const int m0 = blockIdx.x * 256 + wid * 64;
    const float* xb = x + (size_t)n * C_ * M_;

    f32x4 acc[4][4];
    #pragma unroll
    for (int mt = 0; mt < 4; ++mt)
        #pragma unroll
        for (int dt = 0; dt < 4; ++dt) acc[mt][dt] = f32x4{0.f, 0.f, 0.f, 0.f};

    #pragma unroll
    for (int kc = 0; kc < 4; ++kc) {
        const int c0 = kc * 16 + oct * 4;
        s16x4 bh[4], bl[4];
        #pragma unroll
        for (int dt = 0; dt < 4; ++dt) {
            const float* wb = W + (size_t)c0 * C_ + dt * 16 + l15;
            float w0 = wb[0], w1 = wb[C_], w2 = wb[2 * C_], w3 = wb[3 * C_];
            bh[dt] = mk_hi(w0, w1, w2, w3);
            bl[dt] = mk_lo(w0, w1, w2, w3);
        }
        #pragma unroll
        for (int mt = 0; mt < 4; ++mt) {
            const float* xc = xb + (size_t)c0 * M_ + m0 + mt * 16 + l15;
            float x0 = xc[0], x1 = xc[M_], x2 = xc[2 * (size_t)M_], x3 = xc[3 * (size_t)M_];
            s16x4 ah = mk_hi(x0, x1, x2, x3);
            s16x4 al = mk_lo(x0, x1, x2, x3);
            #pragma unroll
            for (int dt = 0; dt < 4; ++dt) {
                acc[mt][dt] = mfma16(ah, bh[dt], acc[mt][dt]);
                acc[mt][dt] = mfma16(ah, bl[dt], acc[mt][dt]);
                acc[mt][dt] = mfma16(al, bh[dt], acc[mt][dt]);
            }
        }
    }
    float* ob = xp + ((size_t)n * M_ + m0) * C_;
    #pragma unroll
    for (int mt = 0; mt < 4; ++mt)
        #pragma unroll
        for (int dt = 0; dt < 4; ++dt)
            #pragma unroll
            for (int r = 0; r < 4; ++r)
                ob[(size_t)(mt * 16 + oct * 4 + r) * C_ + dt * 16 + l15] = acc[mt][dt][r];
}

// -----------------------------------------------------------------------------
// Kernel B: MFMA attention. One block per (n,v), 512 threads = 8 waves.
// Wave owns 32 s (2 s-tiles).  Per 32-t chunk:
//   [stage X(c+1): global fp32 -> bf16 hi/lo planes [d][t], XOR-swizzled]
//   [kk(c+1): VALU dots (global xp rows x phi-LDS) -> packed u32]
//   [QK(c): swapped mfma(KK, Q) x3 -> exp -> pack -> wave-private P  (b128)]
//   [PV(c): mfma(P, X) x3 -> fp32 acc]   one barrier per chunk.
// Epilogue: l via shfl_xor reduce, store normalized tmp[nv][s][d].
// LDS: P 36864 + union(Q 20480 | X 18432 + KK 5120) + phiT 4352 = 64768 B.
// -----------------------------------------------------------------------------
__global__ __launch_bounds__(512, 4) void attn_kernel(
    const float* __restrict__ xp, const float* __restrict__ alpha,
    const float* __restrict__ phi, float* __restrict__ tmp)
{
    __shared__ unsigned smem[16192];           // 64,768 B
    unsigned* Pu  = smem;                      // [8 waves][32 s][36 u32]
    unsigned* Qu  = smem + 9216;               // [256 s][20 u32]   (prologue)
    unsigned* Xu  = smem + 9216;               // [2 buf][2 pl][64 d][18 u32]
    unsigned* KKu = smem + 9216 + 4608;        // [2 buf][32 t][20 u32]
    float* phiT = (float*)(smem + 15104);      // [16 e][68 c] f32
    float* alT  = (float*)smem;                // [16 e][68 c] f32 (aliases P)

    const int tid = threadIdx.x;
    const int lane = tid & 63;
    const int wid = tid >> 6;
    const int l15 = lane & 15;
    const int oct = lane >> 4;
    const int nv = blockIdx.x;
    const int n = nv / V_, v = nv - n * V_;
    const float* xpb = xp + (size_t)n * M_ * C_ + (size_t)v * C_;

    // ---- phase A: stage alphaT (x 1/16 folded) + phiT ----
    for (int i = tid; i < 1024; i += 512) {
        int c = i >> 4, e = i & 15;
        alT[e * 68 + c]  = alpha[i] * 0.0625f;
        phiT[e * 68 + c] = phi[i];
    }
    __syncthreads();

    // ---- phase B: q-dots (fp32) -> packed Q_lds ----
    {
        int s = tid >> 1, eh = tid & 1;
        const float* xr = xpb + (size_t)(2 * s) * RS_;
        const float* ab = alT + (eh * 8) * 68;
        float qa[8] = {0.f, 0.f, 0.f, 0.f, 0.f, 0.f, 0.f, 0.f};
        #pragma unroll
        for (int c4 = 0; c4 < 16; ++c4) {
            float4 xv = *(const float4*)(xr + c4 * 4);
            #pragma unroll
            for (int j = 0; j < 8; ++j) {
                float4 av = *(const float4*)(ab + j * 68 + c4 * 4);
                qa[j] += xv.x * av.x + xv.y * av.y + xv.z * av.z + xv.w * av.w;
            }
        }
        unsigned* qp = Qu + s * 20 + eh * 8;
        *(uint4*)(qp)     = uint4{packhl(qa[0]), packhl(qa[1]), packhl(qa[2]), packhl(qa[3])};
        *(uint4*)(qp + 4) = uint4{packhl(qa[4]), packhl(qa[5]), packhl(qa[6]), packhl(qa[7])};
    }
    __syncthreads();

    // ---- phase C: Q fragments to registers (B-frag: col=l15=s, k=e=oct*4+j) ----
    const int s0w = wid * 32;
    s16x4 qh[2], ql[2];
    #pragma unroll
    for (int st = 0; st < 2; ++st) {
        uint4 qv = *(const uint4*)(Qu + (size_t)(s0w + st * 16 + l15) * 20 + oct * 4);
        qh[st] = hi4(qv); ql[st] = lo4(qv);
    }
    __syncthreads();   // Q region is reused by X/KK below

    // ---- staging helpers ----
    auto STAGE = [&](int ch, int buf) {
        int t = tid >> 4, d4 = tid & 15;
        float4 xv = *(const float4*)(xpb + (size_t)(ch * 32 + t) * RS_ + d4 * 4);
        unsigned short* Xh = (unsigned short*)(Xu + buf * 2304);
        unsigned short* Xl = (unsigned short*)(Xu + buf * 2304 + 1152);
        float vals[4] = {xv.x, xv.y, xv.z, xv.w};
        #pragma unroll
        for (int i = 0; i < 4; ++i) {
            int d = d4 * 4 + i;
            int tp = t ^ ((d & 7) << 2);
            Xh[d * 36 + tp] = bhi(vals[i]);
            Xl[d * 36 + tp] = blo(vals[i]);
        }
    };
    auto KKDOTS = [&](int ch, int buf) {
        int t = tid & 31, e = tid >> 5;
        const float* xr = xpb + (size_t)(ch * 32 + t) * RS_;
        const float* pb = phiT + e * 68;
        float a = 0.f;
        #pragma unroll
        for (int c4 = 0; c4 < 16; ++c4) {
            float4 xv = *(const float4*)(xr + c4 * 4);
            float4 pv = *(const float4*)(pb + c4 * 4);
            a += xv.x * pv.x + xv.y * pv.y + xv.z * pv.z + xv.w * pv.w;
        }
        KKu[buf * 640 + t * 20 + e] = packhl(a);
    };

    STAGE(0, 0); KKDOTS(0, 0);
    __syncthreads();

    f32x4 acc[2][4];
    #pragma unroll
    for (int st = 0; st < 2; ++st)
        #pragma unroll
        for (int dt = 0; dt < 4; ++dt) acc[st][dt] = f32x4{0.f, 0.f, 0.f, 0.f};
    float lp[2] = {0.f, 0.f};
    unsigned* Pw = Pu + wid * 1152;

    for (int c = 0; c < 16; ++c) {
        const int cur = c & 1;
        if (c < 15) { STAGE(c + 1, cur ^ 1); KKDOTS(c + 1, cur ^ 1); }

        // ---- QK (swapped: A=KK[t][e], B=Q[s][e] -> D rows=t, cols=s) ----
        s16x4 kh[2], kl[2];
        #pragma unroll
        for (int tt = 0; tt < 2; ++tt) {
            uint4 kf = *(const uint4*)(KKu + cur * 640 + (tt * 16 + l15) * 20 + oct * 4);
            kh[tt] = hi4(kf); kl[tt] = lo4(kf);
        }
        #pragma unroll
        for (int st = 0; st < 2; ++st) {
            #pragma unroll
            for (int tt = 0; tt < 2; ++tt) {
                f32x4 d = {0.f, 0.f, 0.f, 0.f};
                d = mfma16(kh[tt], qh[st], d);
                d = mfma16(kh[tt], ql[st], d);
                d = mfma16(kl[tt], qh[st], d);
                float p0 = __expf(d[0]), p1 = __expf(d[1]);
                float p2 = __expf(d[2]), p3 = __expf(d[3]);
                lp[st] += (p0 + p1) + (p2 + p3);
                *(uint4*)(Pw + (st * 16 + l15) * 36 + tt * 16 + oct * 4) =
                    uint4{packhl(p0), packhl(p1), packhl(p2), packhl(p3)};
            }
        }

        // ---- PV: A=P[s][t], B=X[t][d] (from [d][t] planes, XOR-deswizzled) ----
        const unsigned* Xh32 = Xu + cur * 2304;
        const unsigned* Xl32 = Xu + cur * 2304 + 1152;
        #pragma unroll
        for (int kt = 0; kt < 2; ++kt) {
            s16x4 pah[2], pal[2];
            #pragma unroll
            for (int st = 0; st < 2; ++st) {
                uint4 pv = *(const uint4*)(Pw + (st * 16 + l15) * 36 + kt * 16 + oct * 4);
                pah[st] = hi4(pv); pal[st] = lo4(pv);
            }
            #pragma unroll
            for (int dt = 0; dt < 4; ++dt) {
                int d = dt * 16 + l15;
                int g4 = (kt * 16 + oct * 4) ^ ((d & 7) << 2);
                int i0 = d * 18 + (g4 >> 1);
                unsigned xa = Xh32[i0], xb2 = Xh32[i0 + 1];
                s16x4 xh = s16x4{(short)(xa & 0xffffu), (short)(xa >> 16),
                                 (short)(xb2 & 0xffffu), (short)(xb2 >> 16)};
                xa = Xl32[i0]; xb2 = Xl32[i0 + 1];
                s16x4 xl = s16x4{(short)(xa & 0xffffu), (short)(xa >> 16),
                                 (short)(xb2 & 0xffffu), (short)(xb2 >> 16)};
                #pragma unroll
                for (int st = 0; st < 2; ++st) {
                    acc[st][dt] = mfma16(pah[st], xh, acc[st][dt]);
                    acc[st][dt] = mfma16(pah[st], xl, acc[st][dt]);
                    acc[st][dt] = mfma16(pal[st], xh, acc[st][dt]);
                }
            }
        }
        __syncthreads();
    }

    // ---- epilogue: reduce l across oct-lanes, normalize, store ----
    #pragma unroll
    for (int st = 0; st < 2; ++st) {
        lp[st] += __shfl_xor(lp[st], 16);
        lp[st] += __shfl_xor(lp[st], 32);
    }
    float* ob = tmp + (size_t)nv * S_ * C_;
    #pragma unroll
    for (int st = 0; st < 2; ++st) {
        float rl[4];
        #pragma unroll
        for (int r = 0; r < 4; ++r)
            rl[r] = 1.0f / __shfl(lp[st], (lane & 48) | (oct * 4 + r));
        #pragma unroll
        for (int dt = 0; dt < 4; ++dt)
            #pragma unroll
            for (int r = 0; r < 4; ++r) {
                int s = s0w + st * 16 + oct * 4 + r;
                ob[(size_t)s * C_ + dt * 16 + l15] = acc[st][dt][r] * rl[r];
            }
    }
}

// -----------------------------------------------------------------------------
// Kernel C: band + transpose.  tmp[n][v][s][d] (already normalized) + band
// -> out[n][d][s][v].  Block = (n, 8-s chunk), LDS-tiled transposed store.
// -----------------------------------------------------------------------------
__global__ __launch_bounds__(256) void final_kernel(
    const float* __restrict__ tmp, const float* __restrict__ xp,
    const float* __restrict__ kband, float* __restrict__ out)
{
    __shared__ float lt[V_ * 8 * 65];
    __shared__ float kbl[9];
    const int tid = threadIdx.x;
    const int b = blockIdx.x;
    const int n = b >> 5, st = b & 31, s0 = st * 8;
    if (tid < 9) kbl[tid] = kband[tid];
    __syncthreads();

    const float* tb = tmp + ((size_t)n * V_ * S_ + s0) * C_;
    const float* xb = xp + (size_t)n * M_ * C_;
    for (int i = tid; i < V_ * 8 * 16; i += 256) {
        int vv = i >> 7, r = i & 127;
        int si = r >> 4, c4 = (r & 15) * 4;
        int s = s0 + si;
        float4 val = *(const float4*)(tb + ((size_t)vv * S_ + si) * C_ + c4);
        #pragma unroll
        for (int j = 0; j < 9; ++j) {
            int t = 2 * s + j - 4;
            if ((unsigned)t < (unsigned)T_) {
                float kb = kbl[j];
                float4 xv = *(const float4*)(xb + ((size_t)t * V_ + vv) * C_ + c4);
                val.x += kb * xv.x; val.y += kb * xv.y;
                val.z += kb * xv.z; val.w += kb * xv.w;
            }
        }
        float* dst = lt + (vv * 8 + si) * 65 + c4;
        dst[0] = val.x; dst[1] = val.y; dst[2] = val.z; dst[3] = val.w;
    }
    __syncthreads();
    float* ob = out + (size_t)n * (C_ * S_ * V_) + (size_t)s0 * V_;
    for (int i = tid; i < C_ * 8 * V_; i += 256) {
        int d = i / 200;
        int r = i - d * 200;
        int si = r / 25;
        int vv = r - si * 25;
        ob[(size_t)d * (S_ * V_) + si * V_ + vv] = lt[(vv * 8 + si) * 65 + d];
    }
}

// -----------------------------------------------------------------------------
extern "C" void kernel_launch(void* const* d_in, const int* in_sizes, int n_in,
                              void* d_out, int out_size, void* d_ws, size_t ws_size,
                              hipStream_t stream)
{
    const float* x     = (const float*)d_in[0];
    const float* W     = (const float*)d_in[1];
    const float* alpha = (const float*)d_in[2];
    const float* phi   = (const float*)d_in[3];
    const float* kband = (const float*)d_in[4];

    float* xp  = (float*)d_ws;                       // 52,428,800 B
    float* tmp = xp + (size_t)N_ * M_ * C_;          // 26,214,400 B (total 78.6 MB)

    xp_gemm_kernel<<<dim3(M_ / 256, N_), 256, 0, stream>>>(x, W, xp);
    attn_kernel<<<dim3(N_ * V_), 512, 0, stream>>>(xp, alpha, phi, tmp);
    final_kernel<<<dim3(N_ * 32), 256, 0, stream>>>(tmp, xp, kband, (float*)d_out);
}